// Round 7
// baseline (339.562 us; speedup 1.0000x reference)
//
#include <hip/hip_runtime.h>

// B=2048 rows, L=16384, W=30 sliding mean of sigmoid(x)*mask, per-row max.
// Register-double-buffered stream: each wave owns a quarter-row, 8 chunks of
// 512 elems. Chunk c+2's loads issue before chunk c+1's compute and are used
// only AFTER the #pragma-unroll-1 back-edge -> liveness forced by dataflow
// (PHIs), not scheduler hints (R0/1: hints lost, VGPR=20 -> 1 dwordx4 in
// flight -> 2.7 TB/s MLP wall; R4/5: gload_lds paths pinned identically).
// No __syncthreads anywhere (wave-private LDS slices) -> no forced vmcnt(0).
constexpr int Bn   = 2048;
constexpr int L    = 16384;
constexpr int W    = 30;
constexpr int NT   = 256;            // 4 waves / block
constexpr int NW   = NT / 64;        // 4
constexpr int SEG  = L / NW;         // 4096 elems per wave
constexpr int CH   = 512;            // elems per chunk
constexpr int NCH  = SEG / CH;       // 8 chunks per wave
constexpr int SPL  = CH / 64;        // 8 window starts per lane
constexpr int PSZ  = 624;            // padded slice: max pidx(540)=607

typedef float f32x4 __attribute__((ext_vector_type(4)));

// Pad +1 float per 8. Window base for lane l: pidx(8l)=9l, gcd(9,32)=1 ->
// 32 distinct banks per 32-lane phase, 2-way across half-wave: free (m136).
// All window offsets c+(c>>3) are compile-time immediates.
__device__ __forceinline__ int pidx(int j) { return j + (j >> 3); }

__device__ __forceinline__ float sigp(float xv, float mv) {
    // m * 1/(1 + 2^(-x*log2(e)))
    float t = -1.44269504089f * xv;
    float e;
    asm("v_exp_f32 %0, %1" : "=v"(e) : "v"(t));
    return mv * __builtin_amdgcn_rcpf(1.0f + e);
}

__global__ __launch_bounds__(NT, 8)   // <=64 VGPR -> 8 blocks/CU = 32 waves/CU
void winmax_reg(const float* __restrict__ x, const float* __restrict__ m,
                float* __restrict__ out) {
    __shared__ float prob[NW][PSZ];   // 4*624*4 = 9984 B -> LDS never the cap

    const int t   = threadIdx.x;
    const int w   = t >> 6;
    const int l   = t & 63;
    const int row = blockIdx.x;
    const int ts  = w * SEG;

    const float* xr = x + (size_t)row * L + ts;   // wave-uniform base (SGPR)
    const float* mr = m + (size_t)row * L + ts;
    float* pw = &prob[w][0];

    float best = 0.0f;

    // Named ping-pong buffers (rule #20: no runtime-indexed arrays).
    f32x4 xaA, xbA, maA, mbA; float xhA, mhA;
    f32x4 xaB, xbB, maB, mbB; float xhB, mhB;

    // Chunk c covers region elems [c*CH, c*CH+CH); lane l loads [4l,4l+3] and
    // [256+4l, 256+4l+3] from each of x,m (2 coalesced dwordx4 each) plus a
    // 29-float halo (lanes l<29, 1 dword each). Halo past row end (only last
    // wave, last chunk) is skipped -> 0; sigp(0,0)=0 and truncated-window
    // sums are subsets of the valid window at L-W (all terms >=0): can't win.
    auto LOADA = [&](int c) {
        const float* gx = xr + c * CH;
        const float* gm = mr + c * CH;
        xaA = *(const f32x4*)(gx + 4 * l);
        xbA = *(const f32x4*)(gx + 256 + 4 * l);
        maA = *(const f32x4*)(gm + 4 * l);
        mbA = *(const f32x4*)(gm + 256 + 4 * l);
        xhA = 0.0f; mhA = 0.0f;
        if (l < W - 1 && ts + c * CH + CH + l < L) {
            xhA = gx[CH + l];
            mhA = gm[CH + l];
        }
    };
    auto LOADB = [&](int c) {
        const float* gx = xr + c * CH;
        const float* gm = mr + c * CH;
        xaB = *(const f32x4*)(gx + 4 * l);
        xbB = *(const f32x4*)(gx + 256 + 4 * l);
        maB = *(const f32x4*)(gm + 4 * l);
        mbB = *(const f32x4*)(gm + 256 + 4 * l);
        xhB = 0.0f; mhB = 0.0f;
        if (l < W - 1 && ts + c * CH + CH + l < L) {
            xhB = gx[CH + l];
            mhB = gm[CH + l];
        }
    };

    // sigp -> padded prob slice -> in-wave lgkm wait -> sliding windows.
    // Same-wave DS ops are in-order: chunk c's reads are issued before chunk
    // c+1's overwrites, so no barrier is needed (R5 precedent, passed).
    auto WINDOWS = [&]() {
        asm volatile("s_waitcnt lgkmcnt(0)" ::: "memory");   // own writes done
        __builtin_amdgcn_sched_barrier(0);                   // rule #18 fence
        const int base = 9 * l;                              // pidx(8l)
        float sum = 0.0f;
        #pragma unroll
        for (int cc = 0; cc < W; ++cc)
            sum += pw[base + cc + (cc >> 3)];
        float bb = sum;
        #pragma unroll
        for (int i = 1; i < SPL; ++i) {
            const int hi = W - 1 + i, lo = i - 1;
            sum += pw[base + hi + (hi >> 3)] - pw[base + lo + (lo >> 3)];
            bb = fmaxf(bb, sum);
        }
        best = fmaxf(best, bb);
    };
    auto COMPA = [&]() {
        const int p0 = 4 * l + (l >> 1);            // pidx(4l), 4 contiguous
        pw[p0 + 0] = sigp(xaA[0], maA[0]);
        pw[p0 + 1] = sigp(xaA[1], maA[1]);
        pw[p0 + 2] = sigp(xaA[2], maA[2]);
        pw[p0 + 3] = sigp(xaA[3], maA[3]);
        const int p1 = 288 + 4 * l + (l >> 1);      // pidx(256+4l)
        pw[p1 + 0] = sigp(xbA[0], mbA[0]);
        pw[p1 + 1] = sigp(xbA[1], mbA[1]);
        pw[p1 + 2] = sigp(xbA[2], mbA[2]);
        pw[p1 + 3] = sigp(xbA[3], mbA[3]);
        if (l < W - 1) pw[pidx(CH + l)] = sigp(xhA, mhA);
        WINDOWS();
    };
    auto COMPB = [&]() {
        const int p0 = 4 * l + (l >> 1);
        pw[p0 + 0] = sigp(xaB[0], maB[0]);
        pw[p0 + 1] = sigp(xaB[1], maB[1]);
        pw[p0 + 2] = sigp(xaB[2], maB[2]);
        pw[p0 + 3] = sigp(xaB[3], maB[3]);
        const int p1 = 288 + 4 * l + (l >> 1);
        pw[p1 + 0] = sigp(xbB[0], mbB[0]);
        pw[p1 + 1] = sigp(xbB[1], mbB[1]);
        pw[p1 + 2] = sigp(xbB[2], mbB[2]);
        pw[p1 + 3] = sigp(xbB[3], mbB[3]);
        if (l < W - 1) pw[pidx(CH + l)] = sigp(xhB, mhB);
        WINDOWS();
    };

    LOADA(0);
    #pragma unroll 1                   // back-edge is the liveness guarantee
    for (int c = 0; c < NCH; c += 2) {
        LOADB(c + 1);                  // in flight across COMPA (fence below)
        COMPA();                       // consumes A loaded BEFORE the back-edge
        if (c + 2 < NCH) LOADA(c + 2); // in flight across COMPB AND back-edge
        COMPB();
    }

    // ---- Wave max-reduce, one atomic per wave (win_mean >= 0 -> uint order) ----
    best *= (1.0f / W);
    #pragma unroll
    for (int off = 32; off > 0; off >>= 1)
        best = fmaxf(best, __shfl_down(best, off, 64));
    if (l == 0)
        atomicMax((unsigned int*)(out + row), __float_as_uint(best));
}

extern "C" void kernel_launch(void* const* d_in, const int* in_sizes, int n_in,
                              void* d_out, int out_size, void* d_ws, size_t ws_size,
                              hipStream_t stream) {
    const float* x = (const float*)d_in[0];
    const float* m = (const float*)d_in[1];
    float* out = (float*)d_out;
    // out is poisoned 0xAA (negative float as bits) -> must zero for atomicMax.
    hipMemsetAsync(out, 0, Bn * sizeof(float), stream);
    winmax_reg<<<Bn, NT, 0, stream>>>(x, m, out);
}